// Round 11
// baseline (87.567 us; speedup 1.0000x reference)
//
#include <hip/hip_runtime.h>

#define N_NODES 50000
#define N_EDGES 400000
#define F_INP 5
#define HD 256          // HEADS*DIM = 2*128
#define BN_EPS 1e-5f

typedef short v8s __attribute__((ext_vector_type(8)));
typedef float v4f __attribute__((ext_vector_type(4)));
typedef unsigned v4u __attribute__((ext_vector_type(4)));

// ---- workspace layout (float offsets) ----
#define OFF_HBN  0          // N*8  (padded rows: 5 used + 3 pad)
#define OFF_ACC  400000     // N*16 (den0,S0[5],den1,S1[5],cnt,pad3)
#define OFF_BPK  1200000    // 16 tiles * 64 lanes * 2 dwords (k_edge B)
#define OFF_WF   1202048    // 128 rows * 16 floats: Wfuse[0..12], sc, sh, pad
#define OFF_W2P  1204096    // 128*8 padded W2

#define PREP_BLOCKS 3125    // N*16/256

// in-row (16-lane) rotate-add via DPP: row_ror:n = 0x120|n — VALU pipe, no LDS
#define DPP_ROR_F(x, n) \
    __int_as_float(__builtin_amdgcn_update_dpp(0, __float_as_int(x), 0x120 | (n), 0xF, 0xF, false))

// float -> bf16 RNE
__device__ __forceinline__ unsigned short f2bf(float f) {
    unsigned u = __float_as_uint(f);
    return (unsigned short)((u + 0x7FFFu + ((u >> 16) & 1u)) >> 16);
}
__device__ __forceinline__ unsigned pk2(float a, float b) {
    return (unsigned)f2bf(a) | ((unsigned)f2bf(b) << 16);
}

// W_cat[k][c]: k 0..4 = Wl, 5..9 = Wr, 10 = We, 11 = bl+br
__device__ __forceinline__ float wcat(int k, int c, const float* Wl, const float* Wr,
                                      const float* We, const float* bl, const float* br) {
    if (k < 5)   return Wl[k * HD + c];
    if (k < 10)  return Wr[(k - 5) * HD + c];
    if (k == 10) return We[c];
    return bl[c] + br[c];
}

// prep (merged): blocks 0..3124 -> zero acc + BN1 + Bpk pack; blocks 3125..3137
// -> Wfuse row fold (one k per block) + BN2/W2 pack.
__global__ void k_prep(const float* __restrict__ h, const float* __restrict__ g1,
                       const float* __restrict__ be1, const float* __restrict__ rm1,
                       const float* __restrict__ rv1,
                       const float* __restrict__ Wl, const float* __restrict__ bl,
                       const float* __restrict__ Wr, const float* __restrict__ br,
                       const float* __restrict__ We, const float* __restrict__ att,
                       const float* __restrict__ bias_gat,
                       const float* __restrict__ W1, const float* __restrict__ b1,
                       const float* __restrict__ g2, const float* __restrict__ be2,
                       const float* __restrict__ rm2, const float* __restrict__ rv2,
                       const float* __restrict__ W2,
                       float* __restrict__ hbn8, float* __restrict__ acc,
                       unsigned* __restrict__ Bpk,
                       float* __restrict__ Wf, float* __restrict__ W2p) {
    if (blockIdx.x < PREP_BLOCKS) {
        int i = blockIdx.x * blockDim.x + threadIdx.x;
        if (i < N_NODES * 16) acc[i] = 0.f;
        if (i < N_NODES * 8) {
            int f = i & 7, n = i >> 3;
            float v = 0.f;
            if (f < F_INP) {
                float x = h[n * F_INP + f];
                v = (x - rm1[f]) * rsqrtf(rv1[f] + BN_EPS) * g1[f] + be1[f];
            }
            hbn8[i] = v;
        }
        if (i < 1024) {  // B fragment pack: tile t, lane l
            int t = i >> 6, l = i & 63;
            int g = l >> 4, c = t * 16 + (l & 15);
            unsigned d0 = 0, d1 = 0;
            if (g < 3) {
                int kb = 4 * g;
                d0 = pk2(wcat(kb + 0, c, Wl, Wr, We, bl, br),
                         wcat(kb + 1, c, Wl, Wr, We, bl, br));
                d1 = pk2(wcat(kb + 2, c, Wl, Wr, We, bl, br),
                         wcat(kb + 3, c, Wl, Wr, We, bl, br));
            }
            Bpk[(t * 64 + l) * 2 + 0] = d0;
            Bpk[(t * 64 + l) * 2 + 1] = d1;
        }
        return;
    }
    // pack2 part: Wf[c][k] = (Wx @ W1)[k,c] (+ b1 folded into k=12)
    int k = blockIdx.x - PREP_BLOCKS;
    int c = threadIdx.x;
    if (c >= 128) return;
    const float* base = (k == 0) ? bl
                      : (k == 1) ? bl + 128
                      : (k < 7)  ? Wl + (k - 2) * HD
                      : (k < 12) ? Wl + (k - 7) * HD + 128
                                 : bias_gat;
    float sum = 0.f;
#pragma unroll 8
    for (int d = 0; d < 128; ++d) sum += base[d] * W1[d * 128 + c];
    if (k == 12) sum += b1[c];
    Wf[c * 16 + k] = sum;
    if (k == 0) {
        float sc = g2[c] * rsqrtf(rv2[c] + BN_EPS);
        Wf[c * 16 + 13] = sc;
        Wf[c * 16 + 14] = be2[c] - rm2[c] * sc;
        Wf[c * 16 + 15] = 0.f;
#pragma unroll
        for (int f = 0; f < 8; ++f)
            W2p[c * 8 + f] = (f < 5) ? W2[c * 5 + f] : 0.f;
    }
}

// MFMA edge kernel, zero-bpermute version: 16 edges per wave-iteration.
// A-operand built by direct per-lane gather (L1 broadcast hits), 16-lane
// logit reduce via DPP row_ror adds (VALU pipe), scatter is group-local:
// after the reduce, group g's lanes hold logits of edges 4g..4g+3 and its
// 13 scatter lanes re-gather src/dst/hs[kc] directly from L2.
__launch_bounds__(256)
__global__ void k_edge(const float* __restrict__ hbn8, const int* __restrict__ ei,
                       const float* __restrict__ ew, const unsigned* __restrict__ Bpk,
                       const float* __restrict__ att, float* __restrict__ acc) {
    int lane = threadIdx.x & 63;
    int wv = threadIdx.x >> 6;
    int g = lane >> 4, e16 = lane & 15;

    // hoist B fragments + att (per-wave constants in VGPRs)
    v8s B[16];
    float AT[16];
#pragma unroll
    for (int t = 0; t < 16; ++t) {
        uint2 d = *(const uint2*)&Bpk[(t * 64 + lane) * 2];
        v4u u = {d.x, d.y, 0u, 0u};
        B[t] = __builtin_bit_cast(v8s, u);
        AT[t] = att[t * 16 + e16];
    }

    int wid = blockIdx.x * 4 + wv;
    int nw = gridDim.x * 4;
    const int NT = N_EDGES / 16;

    // scatter role: lane j16 of group g handles moment j16 of edges 4g+0..3
    int j16 = e16;
    bool sact = j16 < 13;
    int kk = (j16 < 6) ? j16 - 1 : j16 - 7;
    int kc = min(max(kk, 0), 4);

    for (int tile = wid; tile < NT; tile += nw) {
        // direct per-lane gather of edge e16's row (4-way redundant, L1 hits)
        int e = tile * 16 + e16;
        int src = ei[e];
        int dst = ei[N_EDGES + e];
        float w = ew[e];
        float4 s4 = *(const float4*)&hbn8[src * 8];
        float hs4 = hbn8[src * 8 + 4];
        float4 d4 = *(const float4*)&hbn8[dst * 8];
        float hd4 = hbn8[dst * 8 + 4];

        // A slots k=4g..4g+3 of X=[hs0..4, hd0..4, w, 1]
        float a0 = (g == 0) ? s4.x : (g == 1) ? hs4  : d4.w;
        float a1 = (g == 0) ? s4.y : (g == 1) ? d4.x : hd4;
        float a2 = (g == 0) ? s4.z : (g == 1) ? d4.y : w;
        float a3 = (g == 0) ? s4.w : (g == 1) ? d4.z : 1.0f;
        unsigned ua0 = (g < 3) ? pk2(a0, a1) : 0u;
        unsigned ua1 = (g < 3) ? pk2(a2, a3) : 0u;
        v4u uav = {ua0, ua1, 0u, 0u};
        v8s A = __builtin_bit_cast(v8s, uav);

        // MFMA + epilogue: p_h[i2] = sum_c att_c * (u + (2/3)|u|), edge 4g+i2
        float p00 = 0.f, p01 = 0.f, p02 = 0.f, p03 = 0.f;
        float p10 = 0.f, p11 = 0.f, p12 = 0.f, p13v = 0.f;
        v4f zero = {0.f, 0.f, 0.f, 0.f};
#pragma unroll
        for (int t = 0; t < 8; ++t) {
            v4f c = __builtin_amdgcn_mfma_f32_16x16x32_bf16(A, B[t], zero, 0, 0, 0);
            p00 += AT[t] * fmaf(0.66666667f, fabsf(c[0]), c[0]);
            p01 += AT[t] * fmaf(0.66666667f, fabsf(c[1]), c[1]);
            p02 += AT[t] * fmaf(0.66666667f, fabsf(c[2]), c[2]);
            p03 += AT[t] * fmaf(0.66666667f, fabsf(c[3]), c[3]);
        }
#pragma unroll
        for (int t = 8; t < 16; ++t) {
            v4f c = __builtin_amdgcn_mfma_f32_16x16x32_bf16(A, B[t], zero, 0, 0, 0);
            p10 += AT[t] * fmaf(0.66666667f, fabsf(c[0]), c[0]);
            p11 += AT[t] * fmaf(0.66666667f, fabsf(c[1]), c[1]);
            p12 += AT[t] * fmaf(0.66666667f, fabsf(c[2]), c[2]);
            p13v += AT[t] * fmaf(0.66666667f, fabsf(c[3]), c[3]);
        }
        // 16-lane rotate-sum via DPP (deterministic, VALU pipe, no LDS)
#pragma unroll
        for (int st = 1; st <= 8; st <<= 1) {
            // st is compile-time after unroll; expand explicitly:
            if (st == 1) {
                p00 += DPP_ROR_F(p00, 1); p01 += DPP_ROR_F(p01, 1);
                p02 += DPP_ROR_F(p02, 1); p03 += DPP_ROR_F(p03, 1);
                p10 += DPP_ROR_F(p10, 1); p11 += DPP_ROR_F(p11, 1);
                p12 += DPP_ROR_F(p12, 1); p13v += DPP_ROR_F(p13v, 1);
            } else if (st == 2) {
                p00 += DPP_ROR_F(p00, 2); p01 += DPP_ROR_F(p01, 2);
                p02 += DPP_ROR_F(p02, 2); p03 += DPP_ROR_F(p03, 2);
                p10 += DPP_ROR_F(p10, 2); p11 += DPP_ROR_F(p11, 2);
                p12 += DPP_ROR_F(p12, 2); p13v += DPP_ROR_F(p13v, 2);
            } else if (st == 4) {
                p00 += DPP_ROR_F(p00, 4); p01 += DPP_ROR_F(p01, 4);
                p02 += DPP_ROR_F(p02, 4); p03 += DPP_ROR_F(p03, 4);
                p10 += DPP_ROR_F(p10, 4); p11 += DPP_ROR_F(p11, 4);
                p12 += DPP_ROR_F(p12, 4); p13v += DPP_ROR_F(p13v, 4);
            } else {
                p00 += DPP_ROR_F(p00, 8); p01 += DPP_ROR_F(p01, 8);
                p02 += DPP_ROR_F(p02, 8); p03 += DPP_ROR_F(p03, 8);
                p10 += DPP_ROR_F(p10, 8); p11 += DPP_ROR_F(p11, 8);
                p12 += DPP_ROR_F(p12, 8); p13v += DPP_ROR_F(p13v, 8);
            }
        }
        // every lane of group g now holds full logits of edges 4g+0..3
        float e00 = __expf(0.6f * p00), e01 = __expf(0.6f * p01);
        float e02 = __expf(0.6f * p02), e03 = __expf(0.6f * p03);
        float e10 = __expf(0.6f * p10), e11 = __expf(0.6f * p11);
        float e12 = __expf(0.6f * p12), e13 = __expf(0.6f * p13v);

        // group-local moment scatter: 4 its x (4 groups x 13 lanes)
        if (sact) {
#pragma unroll
            for (int it = 0; it < 4; ++it) {
                int eg = tile * 16 + 4 * g + it;
                int srcg = ei[eg];
                int deg = ei[N_EDGES + eg];
                float hsel = hbn8[srcg * 8 + kc];
                float ex0 = (it == 0) ? e00 : (it == 1) ? e01 : (it == 2) ? e02 : e03;
                float ex1 = (it == 0) ? e10 : (it == 1) ? e11 : (it == 2) ? e12 : e13;
                float base = (j16 < 6) ? ex0 : ex1;
                float v = base * hsel;
                v = (j16 == 0) ? ex0 : v;
                v = (j16 == 6) ? ex1 : v;
                v = (j16 == 12) ? 1.0f : v;
                atomicAdd(&acc[deg * 16 + j16], v);
            }
        }
    }
}

// MLP, all-fp32 VALU (validated R9): one thread per node; 128-channel loop
// streams wave-uniform Wf rows against per-lane M[13] registers.
__launch_bounds__(256)
__global__ void k_mlp(const float* __restrict__ acc, const float* __restrict__ Wf,
                      const float* __restrict__ W2p, const float* __restrict__ b2,
                      float* __restrict__ out) {
    int n = blockIdx.x * blockDim.x + threadIdx.x;
    if (n >= N_NODES) return;
    const float* ar = acc + (size_t)n * 16;
    float4 A0 = *(const float4*)(ar + 0);   // den0 S00 S01 S02
    float4 A1 = *(const float4*)(ar + 4);   // S03 S04 den1 S10
    float4 A2 = *(const float4*)(ar + 8);   // S11 S12 S13 S14
    float cnt = ar[12];
    float r0 = 1.f / (A0.x + 1e-16f);
    float r1 = 1.f / (A1.z + 1e-16f);
    float scale = 0.5f / fmaxf(cnt, 1.f);
    float s0 = scale * r0, s1 = scale * r1;
    float m0 = A0.x * s0, m1 = A1.z * s1;
    float m2 = A0.y * s0, m3 = A0.z * s0, m4 = A0.w * s0, m5 = A1.x * s0, m6 = A1.y * s0;
    float m7 = A1.w * s1, m8 = A2.x * s1, m9 = A2.y * s1, m10 = A2.z * s1, m11 = A2.w * s1;

    float o0 = 0.f, o1 = 0.f, o2 = 0.f, o3 = 0.f, o4 = 0.f;
#pragma unroll 4
    for (int c = 0; c < 128; ++c) {
        const float* wr = &Wf[c * 16];
        float a = wr[12];                    // k12 row (M12 = 1)
        a += m0 * wr[0] + m1 * wr[1] + m2 * wr[2] + m3 * wr[3];
        a += m4 * wr[4] + m5 * wr[5] + m6 * wr[6] + m7 * wr[7];
        a += m8 * wr[8] + m9 * wr[9] + m10 * wr[10] + m11 * wr[11];
        a = fmaf(a, wr[13], wr[14]);         // BN2 folded
        a = fmaxf(a, 0.01f * a);             // lrelu 0.01
        const float* w2 = &W2p[c * 8];
        o0 = fmaf(a, w2[0], o0);
        o1 = fmaf(a, w2[1], o1);
        o2 = fmaf(a, w2[2], o2);
        o3 = fmaf(a, w2[3], o3);
        o4 = fmaf(a, w2[4], o4);
    }
    float* op = out + (size_t)n * 5;
    op[0] = o0 + b2[0];
    op[1] = o1 + b2[1];
    op[2] = o2 + b2[2];
    op[3] = o3 + b2[3];
    op[4] = o4 + b2[4];
}

extern "C" void kernel_launch(void* const* d_in, const int* in_sizes, int n_in,
                              void* d_out, int out_size, void* d_ws, size_t ws_size,
                              hipStream_t stream) {
    const float* h    = (const float*)d_in[0];
    const int*   ei   = (const int*)d_in[1];
    const float* ew   = (const float*)d_in[2];
    const float* g1   = (const float*)d_in[3];
    const float* be1  = (const float*)d_in[4];
    const float* rm1  = (const float*)d_in[5];
    const float* rv1  = (const float*)d_in[6];
    const float* Wl   = (const float*)d_in[7];
    const float* bl   = (const float*)d_in[8];
    const float* Wr   = (const float*)d_in[9];
    const float* br   = (const float*)d_in[10];
    const float* We   = (const float*)d_in[11];
    const float* att  = (const float*)d_in[12];
    const float* bias_gat = (const float*)d_in[13];
    const float* W1   = (const float*)d_in[14];
    const float* b1   = (const float*)d_in[15];
    const float* g2   = (const float*)d_in[16];
    const float* be2  = (const float*)d_in[17];
    const float* rm2  = (const float*)d_in[18];
    const float* rv2  = (const float*)d_in[19];
    const float* W2   = (const float*)d_in[20];
    const float* b2   = (const float*)d_in[21];

    float* ws  = (float*)d_ws;
    float* hbn = ws + OFF_HBN;
    float* acc = ws + OFF_ACC;
    unsigned* Bpk = (unsigned*)(ws + OFF_BPK);
    float* Wf  = ws + OFF_WF;
    float* W2p = ws + OFF_W2P;

    k_prep<<<PREP_BLOCKS + 13, 256, 0, stream>>>(
        h, g1, be1, rm1, rv1, Wl, bl, Wr, br, We, att, bias_gat,
        W1, b1, g2, be2, rm2, rv2, W2, hbn, acc, Bpk, Wf, W2p);
    k_edge<<<1280, 256, 0, stream>>>(hbn, ei, ew, Bpk, att, acc);
    k_mlp<<<(N_NODES + 255) / 256, 256, 0, stream>>>(acc, Wf, W2p, b2, (float*)d_out);
}